// Round 4
// baseline (2620.731 us; speedup 1.0000x reference)
//
#include <hip/hip_runtime.h>
#include <hip/hip_bf16.h>
#include <stdint.h>

#define N_PTS   262144
#define H_DIM   512
#define W_DIM   512
#define N_SEG   16
#define EPS_V   1e-5f

typedef __bf16 bf16_t;
typedef __bf16 bf16x8 __attribute__((ext_vector_type(8)));
typedef float  f32x4  __attribute__((ext_vector_type(4)));

// ---------------- RE layout (ws >= 140026880) ----------------
// idx_map int[4*512*512]   @ 0            (4194304)   entry = (seg<<18)|pos, -1 empty
// cat     bf16[(N+1)*256]  @ 4194304      (134218240) [feat|h1|h2|h3] TILE order; row N = 0
//   bins   int[4096]  alias cat+0
//   cursor int[4096]  alias cat+16384     (dead before cat is written)
// wfrag   bf16[258048]     @ 138412544    (516096)
// perm    int[N]           @ 138928640    (1048576)   entry = (seg<<18)|orig
// stats   floats           @ 139977216    (49664)     <- 128 ints + 4*3072 floats
// ---------------- fallback (R2) layout -----------------------
// idx_map @0, cat @4194304, wfrag @138412544, stats @138928640 (49664)
// stats block: cnt[16]@0 ymin@16 ymax@32 xmin@48 xmax@64 dseg[48]@80
//   sums[3*1024]@128 sumsq@3200 pA@6272 pB@9344

__device__ __forceinline__ unsigned spread5(unsigned v) {
  v &= 31u;
  return (v & 1u) | ((v & 2u) << 1) | ((v & 4u) << 2) | ((v & 8u) << 3) | ((v & 16u) << 4);
}
__device__ __forceinline__ int tile_key(int b, int y, int x) {
  return (b << 10) | (spread5((unsigned)(y >> 4)) << 1) | spread5((unsigned)(x >> 4));
}

__global__ void init_kernel(int* cnt, int* ymin, int* ymax, int* xmin, int* xmax,
                            float* sums, float* sumsq) {
  int t = threadIdx.x;
  if (t < N_SEG) {
    cnt[t] = 0;
    ymin[t] = 0x7fffffff; ymax[t] = (int)0x80000000;
    xmin[t] = 0x7fffffff; xmax[t] = (int)0x80000000;
  }
  for (int i = t; i < 3 * 1024; i += 256) { sums[i] = 0.f; sumsq[i] = 0.f; }
}

// histogram + per-seg bbox/cnt
__global__ void hist_bbox_kernel(const int* __restrict__ indices,
                                 const int* __restrict__ seg,
                                 int* __restrict__ bins,
                                 int* __restrict__ cnt,
                                 int* __restrict__ ymin, int* __restrict__ ymax,
                                 int* __restrict__ xmin, int* __restrict__ xmax) {
  __shared__ int lc[N_SEG], ly0[N_SEG], ly1[N_SEG], lx0[N_SEG], lx1[N_SEG];
  int tid = threadIdx.x;
  if (tid < N_SEG) {
    lc[tid] = 0;
    ly0[tid] = 0x7fffffff; ly1[tid] = (int)0x80000000;
    lx0[tid] = 0x7fffffff; lx1[tid] = (int)0x80000000;
  }
  __syncthreads();
  int i = blockIdx.x * 256 + tid;
  int b = indices[i * 3], y = indices[i * 3 + 1], x = indices[i * 3 + 2];
  int s = seg[i];
  atomicAdd(&bins[tile_key(b, y, x)], 1);
  atomicAdd(&lc[s], 1);
  atomicMin(&ly0[s], y); atomicMax(&ly1[s], y);
  atomicMin(&lx0[s], x); atomicMax(&lx1[s], x);
  __syncthreads();
  if (tid < N_SEG && lc[tid] > 0) {
    atomicAdd(&cnt[tid], lc[tid]);
    atomicMin(&ymin[tid], ly0[tid]); atomicMax(&ymax[tid], ly1[tid]);
    atomicMin(&xmin[tid], lx0[tid]); atomicMax(&xmax[tid], lx1[tid]);
  }
}

// exclusive prefix over 4096 bins -> cursor
__global__ void prefix_kernel(const int* __restrict__ bins, int* __restrict__ cursor) {
  __shared__ int sc[1024];
  int t = threadIdx.x;
  int4 v = *(const int4*)(bins + t * 4);
  int s1 = v.x + v.y, s2 = s1 + v.z, s3 = s2 + v.w;
  sc[t] = s3;
  __syncthreads();
  for (int off = 1; off < 1024; off <<= 1) {
    int x = (t >= off) ? sc[t - off] : 0;
    __syncthreads();
    sc[t] += x;
    __syncthreads();
  }
  int excl = (t > 0) ? sc[t - 1] : 0;
  int4 o; o.x = excl; o.y = excl + v.x; o.z = excl + s1; o.w = excl + s2;
  *(int4*)(cursor + t * 4) = o;
}

__global__ void build_kernel(const int* __restrict__ indices,
                             const int* __restrict__ seg,
                             int* __restrict__ cursor,
                             int* __restrict__ perm,
                             int* __restrict__ idx_map) {
  int i = blockIdx.x * 256 + threadIdx.x;
  int b = indices[i * 3], y = indices[i * 3 + 1], x = indices[i * 3 + 2];
  int sg = seg[i];
  int pos = atomicAdd(&cursor[tile_key(b, y, x)], 1);
  perm[pos] = (sg << 18) | i;
  idx_map[(b * H_DIM + y) * W_DIM + x] = (sg << 18) | pos;
}

__global__ void dilation_kernel(const int* ymin, const int* ymax,
                                const int* xmin, const int* xmax,
                                const int* cnt, int* dseg) {
  int t = threadIdx.x;
  if (t < 48) {
    int r = t >> 4, s = t & 15;
    int rate = (r == 0) ? 1 : (r == 1) ? 3 : 5;
    int d = 1;
    if (cnt[s] > 0) {
      float hr = (float)(ymax[s] - ymin[s]) * (1.0f / H_DIM);
      float wr = (float)(xmax[s] - xmin[s]) * (1.0f / W_DIM);
      d = (int)ceilf(fmaxf(hr, wr) * (float)rate);
      if (d < 1) d = 1;
    }
    dseg[t] = d;
  }
}

// scatter features (orig order, coalesced reads) -> cat rows (tile order)
__global__ void reorder_feats_kernel(const float* __restrict__ feats,
                                     const int* __restrict__ indices,
                                     const int* __restrict__ idx_map,
                                     bf16_t* __restrict__ cat) {
  int g = blockIdx.x * 256 + threadIdx.x;    // N*4
  int orig = g >> 2, q = g & 3;
  int b = indices[orig * 3], y = indices[orig * 3 + 1], x = indices[orig * 3 + 2];
  int pos = idx_map[(b * H_DIM + y) * W_DIM + x] & 0x3FFFF;
  const float4* s = (const float4*)feats + (size_t)orig * 16 + q * 4;
  union { bf16_t h[16]; uint4 u[2]; } o;
#pragma unroll
  for (int j = 0; j < 4; ++j) {
    float4 v = s[j];
    o.h[j * 4 + 0] = (bf16_t)v.x; o.h[j * 4 + 1] = (bf16_t)v.y;
    o.h[j * 4 + 2] = (bf16_t)v.z; o.h[j * 4 + 3] = (bf16_t)v.w;
  }
  uint4* d = (uint4*)(cat + (size_t)pos * 256 + q * 16);
  d[0] = o.u[0]; d[1] = o.u[1];
}

// fp32 -> bf16 strided (fallback path)
__global__ void convert_kernel(const float4* __restrict__ in, bf16_t* __restrict__ dst,
                               int stride) {
  int i = blockIdx.x * 256 + threadIdx.x;
  int pt = i >> 4, g = i & 15;
  float4 v = in[i];
  union { bf16_t h[4]; uint2 u; } o;
  o.h[0] = (bf16_t)v.x; o.h[1] = (bf16_t)v.y;
  o.h[2] = (bf16_t)v.z; o.h[3] = (bf16_t)v.w;
  *(uint2*)(dst + (size_t)pt * stride + g * 4) = o.u;
}

// fallback scatter (plain idx_map) + bbox
__global__ void scatter_kernel(const int* __restrict__ indices,
                               const int* __restrict__ seg,
                               int* __restrict__ idx_map,
                               int* __restrict__ cnt,
                               int* __restrict__ ymin, int* __restrict__ ymax,
                               int* __restrict__ xmin, int* __restrict__ xmax) {
  __shared__ int lc[N_SEG], ly0[N_SEG], ly1[N_SEG], lx0[N_SEG], lx1[N_SEG];
  int tid = threadIdx.x;
  if (tid < N_SEG) {
    lc[tid] = 0;
    ly0[tid] = 0x7fffffff; ly1[tid] = (int)0x80000000;
    lx0[tid] = 0x7fffffff; lx1[tid] = (int)0x80000000;
  }
  __syncthreads();
  int i = blockIdx.x * 256 + tid;
  int b = indices[i * 3], y = indices[i * 3 + 1], x = indices[i * 3 + 2];
  int s = seg[i];
  idx_map[(b * H_DIM + y) * W_DIM + x] = i;
  atomicAdd(&lc[s], 1);
  atomicMin(&ly0[s], y); atomicMax(&ly1[s], y);
  atomicMin(&lx0[s], x); atomicMax(&lx1[s], x);
  __syncthreads();
  if (tid < N_SEG && lc[tid] > 0) {
    atomicAdd(&cnt[tid], lc[tid]);
    atomicMin(&ymin[tid], ly0[tid]); atomicMax(&ymax[tid], ly1[tid]);
    atomicMin(&xmin[tid], lx0[tid]); atomicMax(&xmax[tid], lx1[tid]);
  }
}

// wfrag: [0,110592) branch r at r*36864 [k][kk2][cot][lane][j]
//        [110592,258048) final [k][kk8][cot][lane][j]
__global__ void repack_kernel(const float* __restrict__ w1, const float* __restrict__ w2,
                              const float* __restrict__ w3, const float* __restrict__ wf,
                              bf16_t* __restrict__ wfrag) {
  int e = blockIdx.x * 256 + threadIdx.x;
  if (e < 110592) {
    int s = e / 36864, rem = e % 36864;
    int k = rem >> 12, r2 = rem & 4095;
    int kk = r2 >> 11, r3 = r2 & 2047;
    int cot = r3 >> 9, r4 = r3 & 511;
    int lane = r4 >> 3, j = r4 & 7;
    int c  = kk * 32 + (lane >> 4) * 8 + j;
    int co = cot * 16 + (lane & 15);
    const float* w = (s == 0) ? w1 : (s == 1) ? w2 : w3;
    wfrag[e] = (bf16_t)w[k * 4096 + c * 64 + co];
  } else {
    int ef = e - 110592;
    int k = ef >> 14, r2 = ef & 16383;
    int kk8 = r2 >> 11, r3 = r2 & 2047;
    int cot = r3 >> 9, r4 = r3 & 511;
    int lane = r4 >> 3, j = r4 & 7;
    int c  = kk8 * 32 + (lane >> 4) * 8 + j;
    int co = cot * 16 + (lane & 15);
    wfrag[e] = (bf16_t)wf[k * 16384 + c * 64 + co];
  }
}

// KK=2: 64-ch input (slice 0 of cat); KK=8: 256-ch input
// MODE 0: branch conv -> bf16 slice at hoff; MODE 1: final conv -> out (+bias)
// RE: tile-reordered path (packed idx_map/perm, blk swizzle)
template <int KK, int MODE, bool RE>
__launch_bounds__(256)
__global__ void conv_mfma(const bf16_t* __restrict__ A,
                          const bf16_t* __restrict__ wfrag, int wkstride,
                          const int* __restrict__ indices,
                          const int* __restrict__ seg,
                          const int* __restrict__ idx_map,
                          const int* __restrict__ dseg,
                          const int* __restrict__ perm,
                          float* __restrict__ outf,
                          bf16_t* __restrict__ outh, int hoff,
                          const float* __restrict__ bias) {
  __shared__ int s_nbr[9 * 64];
  __shared__ int s_inf[64];
  const int tid = threadIdx.x;
  int blk = RE ? ((blockIdx.x & 7) * 512 + (blockIdx.x >> 3)) : blockIdx.x;
  const int pt0 = blk * 64;

  if (RE) {
    if (tid < 64) {
      int pe = perm[pt0 + tid];
      int orig = pe & 0x3FFFF;
      int sg = (pe >> 18) & 15;
      int b = indices[orig * 3], y = indices[orig * 3 + 1], x = indices[orig * 3 + 2];
      s_inf[tid] = (sg << 20) | (b << 18) | (y << 9) | x;
    }
    __syncthreads();
  }

  for (int e = tid; e < 576; e += 256) {
    int k = e >> 6, row = e & 63;
    int pt = pt0 + row;
    int b, y, x, sg = 0, d = 1;
    if (RE) {
      int info = s_inf[row];
      x = info & 511; y = (info >> 9) & 511; b = (info >> 18) & 3; sg = (info >> 20) & 15;
      if (MODE == 0) d = dseg[sg];
    } else {
      b = indices[pt * 3]; y = indices[pt * 3 + 1]; x = indices[pt * 3 + 2];
      if (MODE == 0) { sg = seg[pt]; d = dseg[sg]; }
    }
    int ky = (k / 3) - 1, kx = (k % 3) - 1;
    int ny = y + ky * d, nx = x + kx * d;
    int nbr = N_PTS;
    if (ny >= 0 && ny < H_DIM && nx >= 0 && nx < W_DIM) {
      int t2 = idx_map[(b * H_DIM + ny) * W_DIM + nx];
      if (t2 >= 0) {
        if (RE) {
          if (MODE == 0) nbr = (((t2 >> 18) & 15) == sg) ? (t2 & 0x3FFFF) : N_PTS;
          else           nbr = t2 & 0x3FFFF;
        } else {
          if (MODE == 0) nbr = (seg[t2] == sg) ? t2 : N_PTS;
          else           nbr = t2;
        }
      }
    }
    s_nbr[e] = nbr;
  }
  __syncthreads();

  const int lane = tid & 63;
  const int wv = tid >> 6;
  const int m = lane & 15;
  const int quad = lane >> 4;
  const int rowm = wv * 16 + m;

  f32x4 acc[4];
#pragma unroll
  for (int c = 0; c < 4; ++c) { acc[c][0] = 0.f; acc[c][1] = 0.f; acc[c][2] = 0.f; acc[c][3] = 0.f; }

  if constexpr (KK == 2) {
    bf16x8 a[9][2];
#pragma unroll
    for (int k = 0; k < 9; ++k) {
      const bf16_t* ar = A + (size_t)s_nbr[k * 64 + rowm] * 256 + quad * 8;
      a[k][0] = *(const bf16x8*)(ar);
      a[k][1] = *(const bf16x8*)(ar + 32);
    }
#pragma unroll
    for (int k = 0; k < 9; ++k) {
#pragma unroll
      for (int kk = 0; kk < 2; ++kk) {
        const bf16_t* wb = wfrag + k * wkstride + kk * 2048 + lane * 8;
#pragma unroll
        for (int cot = 0; cot < 4; ++cot)
          acc[cot] = __builtin_amdgcn_mfma_f32_16x16x32_bf16(
              a[k][kk], *(const bf16x8*)(wb + cot * 512), acc[cot], 0, 0, 0);
      }
    }
  } else {
    // distance-2 prefetch pipeline over neighbors
    bf16x8 a[3][8];
    {
      const bf16_t* ar0 = A + (size_t)s_nbr[rowm] * 256 + quad * 8;
      const bf16_t* ar1 = A + (size_t)s_nbr[64 + rowm] * 256 + quad * 8;
#pragma unroll
      for (int kk = 0; kk < 8; ++kk) a[0][kk] = *(const bf16x8*)(ar0 + kk * 32);
#pragma unroll
      for (int kk = 0; kk < 8; ++kk) a[1][kk] = *(const bf16x8*)(ar1 + kk * 32);
    }
#pragma unroll
    for (int k = 0; k < 9; ++k) {
      if (k + 2 < 9) {
        const bf16_t* ar = A + (size_t)s_nbr[(k + 2) * 64 + rowm] * 256 + quad * 8;
#pragma unroll
        for (int kk = 0; kk < 8; ++kk) a[(k + 2) % 3][kk] = *(const bf16x8*)(ar + kk * 32);
      }
#pragma unroll
      for (int kk = 0; kk < 8; ++kk) {
        const bf16_t* wb = wfrag + k * wkstride + kk * 2048 + lane * 8;
#pragma unroll
        for (int cot = 0; cot < 4; ++cot)
          acc[cot] = __builtin_amdgcn_mfma_f32_16x16x32_bf16(
              a[k % 3][kk], *(const bf16x8*)(wb + cot * 512), acc[cot], 0, 0, 0);
      }
    }
  }

#pragma unroll
  for (int reg = 0; reg < 4; ++reg) {
    int pt = pt0 + wv * 16 + quad * 4 + reg;
    int opt = pt;
    if (RE && MODE == 1) opt = perm[pt] & 0x3FFFF;
#pragma unroll
    for (int cot = 0; cot < 4; ++cot) {
      int col = cot * 16 + m;
      float v = acc[cot][reg];
      if (MODE == 0) outh[(size_t)pt * 256 + hoff + col] = (bf16_t)v;
      else           outf[(size_t)opt * 64 + col] = v + bias[col];
    }
  }
}

// stats via LDS accumulation (tile order: seg not sorted)
__global__ void stats_lds_kernel(const bf16_t* __restrict__ cat, int off,
                                 const int* __restrict__ perm,
                                 float* __restrict__ sums, float* __restrict__ sumsq) {
  __shared__ float lsum[1024], lsq[1024];
  int tid = threadIdx.x;
  for (int j = tid; j < 1024; j += 256) { lsum[j] = 0.f; lsq[j] = 0.f; }
  __syncthreads();
  int co = tid & 63, pr = tid >> 6;
  int base = blockIdx.x * 4096;
  for (int i = pr; i < 4096; i += 4) {
    int pt = base + i;
    int sg = (perm[pt] >> 18) & 15;
    float v = (float)cat[(size_t)pt * 256 + off + co];
    atomicAdd(&lsum[sg * 64 + co], v);
    atomicAdd(&lsq[sg * 64 + co], v * v);
  }
  __syncthreads();
  for (int j = tid; j < 1024; j += 256) {
    if (lsum[j] != 0.f || lsq[j] != 0.f) {
      atomicAdd(&sums[j], lsum[j]);
      atomicAdd(&sumsq[j], lsq[j]);
    }
  }
}

// fallback: seg sorted, run-based
__global__ void stats_run_kernel(const bf16_t* __restrict__ h, int off,
                                 const int* __restrict__ seg,
                                 float* __restrict__ sums, float* __restrict__ sumsq) {
  int tid = threadIdx.x;
  int co = tid & 63, pr = tid >> 6;
  int base = blockIdx.x * 1024;
  float s = 0.f, s2 = 0.f;
  int cur = seg[base];
  for (int i = pr; i < 1024; i += 4) {
    int pt = base + i;
    int sg = seg[pt];
    float v = (float)h[(size_t)pt * 256 + off + co];
    if (sg != cur) {
      atomicAdd(&sums[cur * 64 + co], s);
      atomicAdd(&sumsq[cur * 64 + co], s2);
      s = 0.f; s2 = 0.f; cur = sg;
    }
    s += v; s2 += v * v;
  }
  atomicAdd(&sums[cur * 64 + co], s);
  atomicAdd(&sumsq[cur * 64 + co], s2);
}

__global__ void params_kernel(const int* __restrict__ cnt, const float* __restrict__ sums,
                              const float* __restrict__ sumsq,
                              float* __restrict__ pA, float* __restrict__ pB) {
  int t = blockIdx.x * 256 + threadIdx.x;
  if (t < 1024) {
    int sgi = t >> 6;
    float c = (float)cnt[sgi];
    float a = 0.f, b = 0.f;
    if (c > 0.f) {
      float mean = sums[t] / c;
      float var = sumsq[t] / c - mean * mean;
      float inv = rsqrtf(var + EPS_V);
      a = inv; b = -mean * inv;
    }
    pA[t] = a; pB[t] = b;
  }
}

template <bool RE>
__global__ void norm_kernel(bf16_t* __restrict__ cat, int off,
                            const int* __restrict__ segsrc,   // RE: perm ; else seg
                            const float* __restrict__ pA, const float* __restrict__ pB) {
  int i = blockIdx.x * 256 + threadIdx.x;   // N*16
  int pt = i >> 4;
  int cg = (i & 15) * 4;
  int sg = RE ? ((segsrc[pt] >> 18) & 15) : segsrc[pt];
  bf16_t* p = cat + (size_t)pt * 256 + off + cg;
  union { bf16_t hh[4]; uint2 u; } v;
  v.u = *(uint2*)p;
#pragma unroll
  for (int j = 0; j < 4; ++j) {
    float f = (float)v.hh[j] * pA[sg * 64 + cg + j] + pB[sg * 64 + cg + j];
    v.hh[j] = (bf16_t)fmaxf(f, 0.f);
  }
  *(uint2*)p = v.u;
}

extern "C" void kernel_launch(void* const* d_in, const int* in_sizes, int n_in,
                              void* d_out, int out_size, void* d_ws, size_t ws_size,
                              hipStream_t stream) {
  const float* feats   = (const float*)d_in[0];
  const int*   indices = (const int*)d_in[1];
  const int*   seg     = (const int*)d_in[2];
  const float* w1 = (const float*)d_in[3];
  const float* w2 = (const float*)d_in[5];
  const float* w3 = (const float*)d_in[7];
  const float* wf = (const float*)d_in[9];
  const float* bf_ = (const float*)d_in[10];
  float* out = (float*)d_out;

  char* ws = (char*)d_ws;
  int*    idx_map = (int*)(ws + 0);
  bf16_t* cat     = (bf16_t*)(ws + 4194304);
  bf16_t* wfrag   = (bf16_t*)(ws + 138412544);

  hipMemsetAsync(idx_map, 0xFF, 4194304, stream);
  hipMemsetAsync((char*)cat + 134217728, 0, 512, stream);   // sentinel row N

  if (ws_size >= 140026880ull) {
    // ---- tile-reordered path ----
    int*   perm  = (int*)(ws + 138928640);
    float* stats = (float*)(ws + 139977216);     // 49664 B: ends 140026880
    int* cnt  = (int*)stats;
    int* ymin = (int*)(stats + 16);
    int* ymax = (int*)(stats + 32);
    int* xmin = (int*)(stats + 48);
    int* xmax = (int*)(stats + 64);
    int* dseg = (int*)(stats + 80);
    float* sums  = stats + 128;
    float* sumsq = stats + 3200;
    float* pA    = stats + 6272;
    float* pB    = stats + 9344;

    int* bins   = (int*)cat;                 // dead before cat written
    int* cursor = (int*)((char*)cat + 16384);

    init_kernel<<<1, 256, 0, stream>>>(cnt, ymin, ymax, xmin, xmax, sums, sumsq);
    hipMemsetAsync(bins, 0, 16384, stream);
    hist_bbox_kernel<<<1024, 256, 0, stream>>>(indices, seg, bins, cnt, ymin, ymax, xmin, xmax);
    prefix_kernel<<<1, 1024, 0, stream>>>(bins, cursor);
    build_kernel<<<1024, 256, 0, stream>>>(indices, seg, cursor, perm, idx_map);
    dilation_kernel<<<1, 64, 0, stream>>>(ymin, ymax, xmin, xmax, cnt, dseg);
    reorder_feats_kernel<<<4096, 256, 0, stream>>>(feats, indices, idx_map, cat);
    repack_kernel<<<1008, 256, 0, stream>>>(w1, w2, w3, wf, wfrag);

    for (int r = 0; r < 3; ++r) {
      conv_mfma<2, 0, true><<<4096, 256, 0, stream>>>(cat, wfrag + (size_t)r * 36864, 4096,
                                                      indices, seg, idx_map, dseg + r * 16, perm,
                                                      nullptr, cat, (r + 1) * 64, nullptr);
      stats_lds_kernel<<<64, 256, 0, stream>>>(cat, (r + 1) * 64, perm,
                                               sums + r * 1024, sumsq + r * 1024);
      params_kernel<<<4, 256, 0, stream>>>(cnt, sums + r * 1024, sumsq + r * 1024,
                                           pA + r * 1024, pB + r * 1024);
      norm_kernel<true><<<16384, 256, 0, stream>>>(cat, (r + 1) * 64, perm,
                                                   pA + r * 1024, pB + r * 1024);
    }
    conv_mfma<8, 1, true><<<4096, 256, 0, stream>>>(cat, wfrag + 110592, 16384,
                                                    indices, seg, idx_map, nullptr, perm,
                                                    out, nullptr, 0, bf_);
  } else {
    // ---- R2 fused path (fallback) ----
    float* stats = (float*)(ws + 138928640);
    int* cnt  = (int*)stats;
    int* ymin = (int*)(stats + 16);
    int* ymax = (int*)(stats + 32);
    int* xmin = (int*)(stats + 48);
    int* xmax = (int*)(stats + 64);
    int* dseg = (int*)(stats + 80);
    float* sums  = stats + 128;
    float* sumsq = stats + 3200;
    float* pA    = stats + 6272;
    float* pB    = stats + 9344;

    init_kernel<<<1, 256, 0, stream>>>(cnt, ymin, ymax, xmin, xmax, sums, sumsq);
    scatter_kernel<<<1024, 256, 0, stream>>>(indices, seg, idx_map, cnt, ymin, ymax, xmin, xmax);
    dilation_kernel<<<1, 64, 0, stream>>>(ymin, ymax, xmin, xmax, cnt, dseg);
    convert_kernel<<<16384, 256, 0, stream>>>((const float4*)feats, cat, 256);
    repack_kernel<<<1008, 256, 0, stream>>>(w1, w2, w3, wf, wfrag);

    for (int r = 0; r < 3; ++r) {
      conv_mfma<2, 0, false><<<4096, 256, 0, stream>>>(cat, wfrag + (size_t)r * 36864, 4096,
                                                       indices, seg, idx_map, dseg + r * 16, nullptr,
                                                       nullptr, cat, (r + 1) * 64, nullptr);
      stats_run_kernel<<<256, 256, 0, stream>>>(cat, (r + 1) * 64, seg,
                                                sums + r * 1024, sumsq + r * 1024);
      params_kernel<<<4, 256, 0, stream>>>(cnt, sums + r * 1024, sumsq + r * 1024,
                                           pA + r * 1024, pB + r * 1024);
      norm_kernel<false><<<16384, 256, 0, stream>>>(cat, (r + 1) * 64, seg,
                                                    pA + r * 1024, pB + r * 1024);
    }
    conv_mfma<8, 1, false><<<4096, 256, 0, stream>>>(cat, wfrag + 110592, 16384,
                                                     indices, seg, idx_map, nullptr, nullptr,
                                                     out, nullptr, 0, bf_);
  }
}

// Round 5
// 878.645 us; speedup vs baseline: 2.9827x; 2.9827x over previous
//
#include <hip/hip_runtime.h>
#include <hip/hip_bf16.h>
#include <stdint.h>

#define N_PTS   262144
#define H_DIM   512
#define W_DIM   512
#define N_SEG   16
#define EPS_V   1e-5f

typedef __bf16 bf16_t;
typedef __bf16 bf16x8 __attribute__((ext_vector_type(8)));
typedef float  f32x4  __attribute__((ext_vector_type(4)));

// ---------------- RE layout (ws >= 140026880) ----------------
// idx_map int[4*512*512]   @ 0            (4194304)   entry = (seg<<18)|pos, -1 empty
// cat     bf16[(N+1)*256]  @ 4194304      (134218240) [feat|h1|h2|h3] TILE order; row N = 0
//   bins   int[4096]  alias cat+0
//   cursor int[4096]  alias cat+16384     (dead before cat is written)
// wfrag   bf16[258048]     @ 138412544    (516096)
// perm    int[N]           @ 138928640    (1048576)   entry = (seg<<18)|orig
// stats   floats           @ 139977216    (49664)
// ---------------- fallback (R2) layout -----------------------
// idx_map @0, cat @4194304, wfrag @138412544, stats @138928640
// stats block: cnt[16]@0 ymin@16 ymax@32 xmin@48 xmax@64 dseg[48]@80
//   sums[3*1024]@128 sumsq@3200 (pA/pB slots unused now)

__device__ __forceinline__ unsigned spread5(unsigned v) {
  v &= 31u;
  return (v & 1u) | ((v & 2u) << 1) | ((v & 4u) << 2) | ((v & 8u) << 3) | ((v & 16u) << 4);
}
__device__ __forceinline__ int tile_key(int b, int y, int x) {
  return (b << 10) | (spread5((unsigned)(y >> 4)) << 1) | spread5((unsigned)(x >> 4));
}

__global__ void init_kernel(int* cnt, int* ymin, int* ymax, int* xmin, int* xmax,
                            float* sums, float* sumsq) {
  int t = threadIdx.x;
  if (t < N_SEG) {
    cnt[t] = 0;
    ymin[t] = 0x7fffffff; ymax[t] = (int)0x80000000;
    xmin[t] = 0x7fffffff; xmax[t] = (int)0x80000000;
  }
  for (int i = t; i < 3 * 1024; i += 256) { sums[i] = 0.f; sumsq[i] = 0.f; }
}

// histogram + per-seg bbox/cnt
__global__ void hist_bbox_kernel(const int* __restrict__ indices,
                                 const int* __restrict__ seg,
                                 int* __restrict__ bins,
                                 int* __restrict__ cnt,
                                 int* __restrict__ ymin, int* __restrict__ ymax,
                                 int* __restrict__ xmin, int* __restrict__ xmax) {
  __shared__ int lc[N_SEG], ly0[N_SEG], ly1[N_SEG], lx0[N_SEG], lx1[N_SEG];
  int tid = threadIdx.x;
  if (tid < N_SEG) {
    lc[tid] = 0;
    ly0[tid] = 0x7fffffff; ly1[tid] = (int)0x80000000;
    lx0[tid] = 0x7fffffff; lx1[tid] = (int)0x80000000;
  }
  __syncthreads();
  int i = blockIdx.x * 256 + tid;
  int b = indices[i * 3], y = indices[i * 3 + 1], x = indices[i * 3 + 2];
  int s = seg[i];
  atomicAdd(&bins[tile_key(b, y, x)], 1);
  atomicAdd(&lc[s], 1);
  atomicMin(&ly0[s], y); atomicMax(&ly1[s], y);
  atomicMin(&lx0[s], x); atomicMax(&lx1[s], x);
  __syncthreads();
  if (tid < N_SEG && lc[tid] > 0) {
    atomicAdd(&cnt[tid], lc[tid]);
    atomicMin(&ymin[tid], ly0[tid]); atomicMax(&ymax[tid], ly1[tid]);
    atomicMin(&xmin[tid], lx0[tid]); atomicMax(&xmax[tid], lx1[tid]);
  }
}

// exclusive prefix over 4096 bins -> cursor
__global__ void prefix_kernel(const int* __restrict__ bins, int* __restrict__ cursor) {
  __shared__ int sc[1024];
  int t = threadIdx.x;
  int4 v = *(const int4*)(bins + t * 4);
  int s1 = v.x + v.y, s2 = s1 + v.z, s3 = s2 + v.w;
  sc[t] = s3;
  __syncthreads();
  for (int off = 1; off < 1024; off <<= 1) {
    int x = (t >= off) ? sc[t - off] : 0;
    __syncthreads();
    sc[t] += x;
    __syncthreads();
  }
  int excl = (t > 0) ? sc[t - 1] : 0;
  int4 o; o.x = excl; o.y = excl + v.x; o.z = excl + s1; o.w = excl + s2;
  *(int4*)(cursor + t * 4) = o;
}

__global__ void build_kernel(const int* __restrict__ indices,
                             const int* __restrict__ seg,
                             int* __restrict__ cursor,
                             int* __restrict__ perm,
                             int* __restrict__ idx_map) {
  int i = blockIdx.x * 256 + threadIdx.x;
  int b = indices[i * 3], y = indices[i * 3 + 1], x = indices[i * 3 + 2];
  int sg = seg[i];
  int pos = atomicAdd(&cursor[tile_key(b, y, x)], 1);
  perm[pos] = (sg << 18) | i;
  idx_map[(b * H_DIM + y) * W_DIM + x] = (sg << 18) | pos;
}

__global__ void dilation_kernel(const int* ymin, const int* ymax,
                                const int* xmin, const int* xmax,
                                const int* cnt, int* dseg) {
  int t = threadIdx.x;
  if (t < 48) {
    int r = t >> 4, s = t & 15;
    int rate = (r == 0) ? 1 : (r == 1) ? 3 : 5;
    int d = 1;
    if (cnt[s] > 0) {
      float hr = (float)(ymax[s] - ymin[s]) * (1.0f / H_DIM);
      float wr = (float)(xmax[s] - xmin[s]) * (1.0f / W_DIM);
      d = (int)ceilf(fmaxf(hr, wr) * (float)rate);
      if (d < 1) d = 1;
    }
    dseg[t] = d;
  }
}

// scatter features (orig order, coalesced reads) -> cat rows (tile order)
__global__ void reorder_feats_kernel(const float* __restrict__ feats,
                                     const int* __restrict__ indices,
                                     const int* __restrict__ idx_map,
                                     bf16_t* __restrict__ cat) {
  int g = blockIdx.x * 256 + threadIdx.x;    // N*4
  int orig = g >> 2, q = g & 3;
  int b = indices[orig * 3], y = indices[orig * 3 + 1], x = indices[orig * 3 + 2];
  int pos = idx_map[(b * H_DIM + y) * W_DIM + x] & 0x3FFFF;
  const float4* s = (const float4*)feats + (size_t)orig * 16 + q * 4;
  union { bf16_t h[16]; uint4 u[2]; } o;
#pragma unroll
  for (int j = 0; j < 4; ++j) {
    float4 v = s[j];
    o.h[j * 4 + 0] = (bf16_t)v.x; o.h[j * 4 + 1] = (bf16_t)v.y;
    o.h[j * 4 + 2] = (bf16_t)v.z; o.h[j * 4 + 3] = (bf16_t)v.w;
  }
  uint4* d = (uint4*)(cat + (size_t)pos * 256 + q * 16);
  d[0] = o.u[0]; d[1] = o.u[1];
}

// fp32 -> bf16 strided (fallback path)
__global__ void convert_kernel(const float4* __restrict__ in, bf16_t* __restrict__ dst,
                               int stride) {
  int i = blockIdx.x * 256 + threadIdx.x;
  int pt = i >> 4, g = i & 15;
  float4 v = in[i];
  union { bf16_t h[4]; uint2 u; } o;
  o.h[0] = (bf16_t)v.x; o.h[1] = (bf16_t)v.y;
  o.h[2] = (bf16_t)v.z; o.h[3] = (bf16_t)v.w;
  *(uint2*)(dst + (size_t)pt * stride + g * 4) = o.u;
}

// fallback scatter (plain idx_map) + bbox
__global__ void scatter_kernel(const int* __restrict__ indices,
                               const int* __restrict__ seg,
                               int* __restrict__ idx_map,
                               int* __restrict__ cnt,
                               int* __restrict__ ymin, int* __restrict__ ymax,
                               int* __restrict__ xmin, int* __restrict__ xmax) {
  __shared__ int lc[N_SEG], ly0[N_SEG], ly1[N_SEG], lx0[N_SEG], lx1[N_SEG];
  int tid = threadIdx.x;
  if (tid < N_SEG) {
    lc[tid] = 0;
    ly0[tid] = 0x7fffffff; ly1[tid] = (int)0x80000000;
    lx0[tid] = 0x7fffffff; lx1[tid] = (int)0x80000000;
  }
  __syncthreads();
  int i = blockIdx.x * 256 + tid;
  int b = indices[i * 3], y = indices[i * 3 + 1], x = indices[i * 3 + 2];
  int s = seg[i];
  idx_map[(b * H_DIM + y) * W_DIM + x] = i;
  atomicAdd(&lc[s], 1);
  atomicMin(&ly0[s], y); atomicMax(&ly1[s], y);
  atomicMin(&lx0[s], x); atomicMax(&lx1[s], x);
  __syncthreads();
  if (tid < N_SEG && lc[tid] > 0) {
    atomicAdd(&cnt[tid], lc[tid]);
    atomicMin(&ymin[tid], ly0[tid]); atomicMax(&ymax[tid], ly1[tid]);
    atomicMin(&xmin[tid], lx0[tid]); atomicMax(&xmax[tid], lx1[tid]);
  }
}

// wfrag: [0,110592) branch r at r*36864 [k][kk2][cot][lane][j]
//        [110592,258048) final [k][kk8][cot][lane][j]
__global__ void repack_kernel(const float* __restrict__ w1, const float* __restrict__ w2,
                              const float* __restrict__ w3, const float* __restrict__ wf,
                              bf16_t* __restrict__ wfrag) {
  int e = blockIdx.x * 256 + threadIdx.x;
  if (e < 110592) {
    int s = e / 36864, rem = e % 36864;
    int k = rem >> 12, r2 = rem & 4095;
    int kk = r2 >> 11, r3 = r2 & 2047;
    int cot = r3 >> 9, r4 = r3 & 511;
    int lane = r4 >> 3, j = r4 & 7;
    int c  = kk * 32 + (lane >> 4) * 8 + j;
    int co = cot * 16 + (lane & 15);
    const float* w = (s == 0) ? w1 : (s == 1) ? w2 : w3;
    wfrag[e] = (bf16_t)w[k * 4096 + c * 64 + co];
  } else {
    int ef = e - 110592;
    int k = ef >> 14, r2 = ef & 16383;
    int kk8 = r2 >> 11, r3 = r2 & 2047;
    int cot = r3 >> 9, r4 = r3 & 511;
    int lane = r4 >> 3, j = r4 & 7;
    int c  = kk8 * 32 + (lane >> 4) * 8 + j;
    int co = cot * 16 + (lane & 15);
    wfrag[e] = (bf16_t)wf[k * 16384 + c * 64 + co];
  }
}

// KK=2: 64-ch input (slice 0 of cat); KK=8: 256-ch input
// MODE 0: branch conv -> bf16 slice at hoff; MODE 1: final conv -> out (+bias)
// RE: tile-reordered path (packed idx_map/perm, blk swizzle)
template <int KK, int MODE, bool RE>
__launch_bounds__(256)
__global__ void conv_mfma(const bf16_t* __restrict__ A,
                          const bf16_t* __restrict__ wfrag, int wkstride,
                          const int* __restrict__ indices,
                          const int* __restrict__ seg,
                          const int* __restrict__ idx_map,
                          const int* __restrict__ dseg,
                          const int* __restrict__ perm,
                          float* __restrict__ outf,
                          bf16_t* __restrict__ outh, int hoff,
                          const float* __restrict__ bias) {
  __shared__ int s_nbr[9 * 64];
  __shared__ int s_inf[64];
  const int tid = threadIdx.x;
  int blk = RE ? ((blockIdx.x & 7) * 512 + (blockIdx.x >> 3)) : blockIdx.x;
  const int pt0 = blk * 64;

  if (RE) {
    if (tid < 64) {
      int pe = perm[pt0 + tid];
      int orig = pe & 0x3FFFF;
      int sg = (pe >> 18) & 15;
      int b = indices[orig * 3], y = indices[orig * 3 + 1], x = indices[orig * 3 + 2];
      s_inf[tid] = (sg << 20) | (b << 18) | (y << 9) | x;
    }
    __syncthreads();
  }

  for (int e = tid; e < 576; e += 256) {
    int k = e >> 6, row = e & 63;
    int pt = pt0 + row;
    int b, y, x, sg = 0, d = 1;
    if (RE) {
      int info = s_inf[row];
      x = info & 511; y = (info >> 9) & 511; b = (info >> 18) & 3; sg = (info >> 20) & 15;
      if (MODE == 0) d = dseg[sg];
    } else {
      b = indices[pt * 3]; y = indices[pt * 3 + 1]; x = indices[pt * 3 + 2];
      if (MODE == 0) { sg = seg[pt]; d = dseg[sg]; }
    }
    int ky = (k / 3) - 1, kx = (k % 3) - 1;
    int ny = y + ky * d, nx = x + kx * d;
    int nbr = N_PTS;
    if (ny >= 0 && ny < H_DIM && nx >= 0 && nx < W_DIM) {
      int t2 = idx_map[(b * H_DIM + ny) * W_DIM + nx];
      if (t2 >= 0) {
        if (RE) {
          if (MODE == 0) nbr = (((t2 >> 18) & 15) == sg) ? (t2 & 0x3FFFF) : N_PTS;
          else           nbr = t2 & 0x3FFFF;
        } else {
          if (MODE == 0) nbr = (seg[t2] == sg) ? t2 : N_PTS;
          else           nbr = t2;
        }
      }
    }
    s_nbr[e] = nbr;
  }
  __syncthreads();

  const int lane = tid & 63;
  const int wv = tid >> 6;
  const int m = lane & 15;
  const int quad = lane >> 4;
  const int rowm = wv * 16 + m;

  f32x4 acc[4];
#pragma unroll
  for (int c = 0; c < 4; ++c) { acc[c][0] = 0.f; acc[c][1] = 0.f; acc[c][2] = 0.f; acc[c][3] = 0.f; }

  if constexpr (KK == 2) {
    bf16x8 a[9][2];
#pragma unroll
    for (int k = 0; k < 9; ++k) {
      const bf16_t* ar = A + (size_t)s_nbr[k * 64 + rowm] * 256 + quad * 8;
      a[k][0] = *(const bf16x8*)(ar);
      a[k][1] = *(const bf16x8*)(ar + 32);
    }
#pragma unroll
    for (int k = 0; k < 9; ++k) {
#pragma unroll
      for (int kk = 0; kk < 2; ++kk) {
        const bf16_t* wb = wfrag + k * wkstride + kk * 2048 + lane * 8;
#pragma unroll
        for (int cot = 0; cot < 4; ++cot)
          acc[cot] = __builtin_amdgcn_mfma_f32_16x16x32_bf16(
              a[k][kk], *(const bf16x8*)(wb + cot * 512), acc[cot], 0, 0, 0);
      }
    }
  } else {
    // distance-2 prefetch pipeline over neighbors
    bf16x8 a[3][8];
    {
      const bf16_t* ar0 = A + (size_t)s_nbr[rowm] * 256 + quad * 8;
      const bf16_t* ar1 = A + (size_t)s_nbr[64 + rowm] * 256 + quad * 8;
#pragma unroll
      for (int kk = 0; kk < 8; ++kk) a[0][kk] = *(const bf16x8*)(ar0 + kk * 32);
#pragma unroll
      for (int kk = 0; kk < 8; ++kk) a[1][kk] = *(const bf16x8*)(ar1 + kk * 32);
    }
#pragma unroll
    for (int k = 0; k < 9; ++k) {
      if (k + 2 < 9) {
        const bf16_t* ar = A + (size_t)s_nbr[(k + 2) * 64 + rowm] * 256 + quad * 8;
#pragma unroll
        for (int kk = 0; kk < 8; ++kk) a[(k + 2) % 3][kk] = *(const bf16x8*)(ar + kk * 32);
      }
#pragma unroll
      for (int kk = 0; kk < 8; ++kk) {
        const bf16_t* wb = wfrag + k * wkstride + kk * 2048 + lane * 8;
#pragma unroll
        for (int cot = 0; cot < 4; ++cot)
          acc[cot] = __builtin_amdgcn_mfma_f32_16x16x32_bf16(
              a[k % 3][kk], *(const bf16x8*)(wb + cot * 512), acc[cot], 0, 0, 0);
      }
    }
  }

#pragma unroll
  for (int reg = 0; reg < 4; ++reg) {
    int pt = pt0 + wv * 16 + quad * 4 + reg;
    int opt = pt;
    if (RE && MODE == 1) opt = perm[pt] & 0x3FFFF;
#pragma unroll
    for (int cot = 0; cot < 4; ++cot) {
      int col = cot * 16 + m;
      float v = acc[cot][reg];
      if (MODE == 0) outh[(size_t)pt * 256 + hoff + col] = (bf16_t)v;
      else           outf[(size_t)opt * 64 + col] = v + bias[col];
    }
  }
}

// RE-path stats: iterate ORIGINAL order (seg sorted -> register runs),
// gather cat row via idx_map. All control loads are wave-uniform.
__global__ void stats_orig_kernel(const bf16_t* __restrict__ cat, int off,
                                  const int* __restrict__ indices,
                                  const int* __restrict__ seg,
                                  const int* __restrict__ idx_map,
                                  float* __restrict__ sums, float* __restrict__ sumsq) {
  int tid = threadIdx.x;
  int co = tid & 63, pr = tid >> 6;
  int base = blockIdx.x * 512;
  float s = 0.f, s2 = 0.f;
  int cur = seg[base];
#pragma unroll 4
  for (int i = pr; i < 512; i += 4) {
    int o = base + i;
    int sg = seg[o];
    int b = indices[o * 3], y = indices[o * 3 + 1], x = indices[o * 3 + 2];
    int pos = idx_map[(b * H_DIM + y) * W_DIM + x] & 0x3FFFF;
    float v = (float)cat[(size_t)pos * 256 + off + co];
    if (sg != cur) {
      atomicAdd(&sums[cur * 64 + co], s);
      atomicAdd(&sumsq[cur * 64 + co], s2);
      s = 0.f; s2 = 0.f; cur = sg;
    }
    s += v; s2 += v * v;
  }
  atomicAdd(&sums[cur * 64 + co], s);
  atomicAdd(&sumsq[cur * 64 + co], s2);
}

// fallback stats: orig order, h contiguous
__global__ void stats_run_kernel(const bf16_t* __restrict__ h, int off,
                                 const int* __restrict__ seg,
                                 float* __restrict__ sums, float* __restrict__ sumsq) {
  int tid = threadIdx.x;
  int co = tid & 63, pr = tid >> 6;
  int base = blockIdx.x * 1024;
  float s = 0.f, s2 = 0.f;
  int cur = seg[base];
#pragma unroll 4
  for (int i = pr; i < 1024; i += 4) {
    int pt = base + i;
    int sg = seg[pt];
    float v = (float)h[(size_t)pt * 256 + off + co];
    if (sg != cur) {
      atomicAdd(&sums[cur * 64 + co], s);
      atomicAdd(&sumsq[cur * 64 + co], s2);
      s = 0.f; s2 = 0.f; cur = sg;
    }
    s += v; s2 += v * v;
  }
  atomicAdd(&sums[cur * 64 + co], s);
  atomicAdd(&sumsq[cur * 64 + co], s2);
}

// norm with inline params (mean/var/rsqrt from sums tables; tables are L1-hot)
template <bool RE>
__global__ void norm_kernel(bf16_t* __restrict__ cat, int off,
                            const int* __restrict__ segsrc,   // RE: perm ; else seg
                            const int* __restrict__ cnt,
                            const float* __restrict__ sums,
                            const float* __restrict__ sumsq) {
  int i = blockIdx.x * 256 + threadIdx.x;   // N*16
  int pt = i >> 4;
  int cg = (i & 15) * 4;
  int sg = RE ? ((segsrc[pt] >> 18) & 15) : segsrc[pt];
  float rc = 1.0f / (float)cnt[sg];
  bf16_t* p = cat + (size_t)pt * 256 + off + cg;
  union { bf16_t hh[4]; uint2 u; } v;
  v.u = *(uint2*)p;
#pragma unroll
  for (int j = 0; j < 4; ++j) {
    float mean = sums[sg * 64 + cg + j] * rc;
    float var  = sumsq[sg * 64 + cg + j] * rc - mean * mean;
    float inv  = rsqrtf(var + EPS_V);
    float f = ((float)v.hh[j] - mean) * inv;
    v.hh[j] = (bf16_t)fmaxf(f, 0.f);
  }
  *(uint2*)p = v.u;
}

extern "C" void kernel_launch(void* const* d_in, const int* in_sizes, int n_in,
                              void* d_out, int out_size, void* d_ws, size_t ws_size,
                              hipStream_t stream) {
  const float* feats   = (const float*)d_in[0];
  const int*   indices = (const int*)d_in[1];
  const int*   seg     = (const int*)d_in[2];
  const float* w1 = (const float*)d_in[3];
  const float* w2 = (const float*)d_in[5];
  const float* w3 = (const float*)d_in[7];
  const float* wf = (const float*)d_in[9];
  const float* bf_ = (const float*)d_in[10];
  float* out = (float*)d_out;

  char* ws = (char*)d_ws;
  int*    idx_map = (int*)(ws + 0);
  bf16_t* cat     = (bf16_t*)(ws + 4194304);
  bf16_t* wfrag   = (bf16_t*)(ws + 138412544);

  hipMemsetAsync(idx_map, 0xFF, 4194304, stream);
  hipMemsetAsync((char*)cat + 134217728, 0, 512, stream);   // sentinel row N

  if (ws_size >= 140026880ull) {
    // ---- tile-reordered path ----
    int*   perm  = (int*)(ws + 138928640);
    float* stats = (float*)(ws + 139977216);
    int* cnt  = (int*)stats;
    int* ymin = (int*)(stats + 16);
    int* ymax = (int*)(stats + 32);
    int* xmin = (int*)(stats + 48);
    int* xmax = (int*)(stats + 64);
    int* dseg = (int*)(stats + 80);
    float* sums  = stats + 128;
    float* sumsq = stats + 3200;

    int* bins   = (int*)cat;                 // dead before cat written
    int* cursor = (int*)((char*)cat + 16384);

    init_kernel<<<1, 256, 0, stream>>>(cnt, ymin, ymax, xmin, xmax, sums, sumsq);
    hipMemsetAsync(bins, 0, 16384, stream);
    hist_bbox_kernel<<<1024, 256, 0, stream>>>(indices, seg, bins, cnt, ymin, ymax, xmin, xmax);
    prefix_kernel<<<1, 1024, 0, stream>>>(bins, cursor);
    build_kernel<<<1024, 256, 0, stream>>>(indices, seg, cursor, perm, idx_map);
    dilation_kernel<<<1, 64, 0, stream>>>(ymin, ymax, xmin, xmax, cnt, dseg);
    reorder_feats_kernel<<<4096, 256, 0, stream>>>(feats, indices, idx_map, cat);
    repack_kernel<<<1008, 256, 0, stream>>>(w1, w2, w3, wf, wfrag);

    for (int r = 0; r < 3; ++r) {
      conv_mfma<2, 0, true><<<4096, 256, 0, stream>>>(cat, wfrag + (size_t)r * 36864, 4096,
                                                      indices, seg, idx_map, dseg + r * 16, perm,
                                                      nullptr, cat, (r + 1) * 64, nullptr);
      stats_orig_kernel<<<512, 256, 0, stream>>>(cat, (r + 1) * 64, indices, seg, idx_map,
                                                 sums + r * 1024, sumsq + r * 1024);
      norm_kernel<true><<<16384, 256, 0, stream>>>(cat, (r + 1) * 64, perm, cnt,
                                                   sums + r * 1024, sumsq + r * 1024);
    }
    conv_mfma<8, 1, true><<<4096, 256, 0, stream>>>(cat, wfrag + 110592, 16384,
                                                    indices, seg, idx_map, nullptr, perm,
                                                    out, nullptr, 0, bf_);
  } else {
    // ---- R2 fused path (fallback) ----
    float* stats = (float*)(ws + 138928640);
    int* cnt  = (int*)stats;
    int* ymin = (int*)(stats + 16);
    int* ymax = (int*)(stats + 32);
    int* xmin = (int*)(stats + 48);
    int* xmax = (int*)(stats + 64);
    int* dseg = (int*)(stats + 80);
    float* sums  = stats + 128;
    float* sumsq = stats + 3200;

    init_kernel<<<1, 256, 0, stream>>>(cnt, ymin, ymax, xmin, xmax, sums, sumsq);
    scatter_kernel<<<1024, 256, 0, stream>>>(indices, seg, idx_map, cnt, ymin, ymax, xmin, xmax);
    dilation_kernel<<<1, 64, 0, stream>>>(ymin, ymax, xmin, xmax, cnt, dseg);
    convert_kernel<<<16384, 256, 0, stream>>>((const float4*)feats, cat, 256);
    repack_kernel<<<1008, 256, 0, stream>>>(w1, w2, w3, wf, wfrag);

    for (int r = 0; r < 3; ++r) {
      conv_mfma<2, 0, false><<<4096, 256, 0, stream>>>(cat, wfrag + (size_t)r * 36864, 4096,
                                                       indices, seg, idx_map, dseg + r * 16, nullptr,
                                                       nullptr, cat, (r + 1) * 64, nullptr);
      stats_run_kernel<<<256, 256, 0, stream>>>(cat, (r + 1) * 64, seg,
                                                sums + r * 1024, sumsq + r * 1024);
      norm_kernel<false><<<16384, 256, 0, stream>>>(cat, (r + 1) * 64, seg, cnt,
                                                    sums + r * 1024, sumsq + r * 1024);
    }
    conv_mfma<8, 1, false><<<4096, 256, 0, stream>>>(cat, wfrag + 110592, 16384,
                                                     indices, seg, idx_map, nullptr, nullptr,
                                                     out, nullptr, 0, bf_);
  }
}